// Round 8
// baseline (347.418 us; speedup 1.0000x reference)
//
#include <hip/hip_runtime.h>

// LSTM B=2048, T=512, I=1, H=64, O=1 (PyTorch gate order i,f,g,o).
// v7 = v4 two-phase structure at NBW=2 -> grid 1024 = 4 WGs/CU (4 chains/CU,
// 4 waves/SIMD) for latency hiding; that's the lever (v4/v5/v6 all ~250-280us
// at 2 chains/CU regardless of barrier structure).
//   Phase 1: wave wv owns gate TYPE wv (64 rows = 4 N-tiles), W frags in
//     32 VGPRs pre-scaled by -log2e (i,f,o) / -2log2e (g) so activations are
//     rcp(1+exp2(g)) with no pre-multiply. G = H @ W^T: A = h (LDS fp16,
//     XOR-swizzled), C-init = x*w_ih + bias (C rows = batches).
//   Phase 2: 128 threads, 1 state/lane (pb=tid&1, pj=tid>>1); g_raw reads
//     are g_raw[g*128 + tid] -> stride-1, conflict-free. fp16 h write-back.
//   Two barriers/step (gate handoff + h handoff), both exchanges minimal.
// (Round 7 was an infra failure — container acquire — resubmitting unchanged.)

typedef float    f32x4 __attribute__((ext_vector_type(4)));
typedef _Float16 f16x8 __attribute__((ext_vector_type(8)));

namespace {
constexpr int Bsz = 2048;
constexpr int Tsz = 512;
constexpr int NBW = 2;    // batches per workgroup -> grid 1024, 4 WG/CU
}

__device__ __forceinline__ float rcp_f(float v)  { return __builtin_amdgcn_rcpf(v); }
__device__ __forceinline__ float exp2_f(float v) { return __builtin_amdgcn_exp2f(v); }

// gs = -log2e * gate -> sigmoid(gate); saturates at +-inf
__device__ __forceinline__ float sigm_s(float gs)  { return rcp_f(1.0f + exp2_f(gs)); }
// gs = -2log2e * gate -> tanh(gate)
__device__ __forceinline__ float tanh_s(float gs)  { return fmaf(2.0f, rcp_f(1.0f + exp2_f(gs)), -1.0f); }
// plain tanh for cell state
__device__ __forceinline__ float tanh_plain(float v) {
    return fmaf(2.0f, rcp_f(1.0f + exp2_f(v * -2.88539008178f)), -1.0f);
}

__global__ __launch_bounds__(256, 4)
void lstm_v7(const float* __restrict__ x,      // [B,T]
             const float* __restrict__ w_ih,   // [256]
             const float* __restrict__ w_hh,   // [256,64]
             const float* __restrict__ b_ih,   // [256]
             const float* __restrict__ b_hh,   // [256]
             const float* __restrict__ w_lin,  // [64]
             const float* __restrict__ b_lin,  // [1]
             float* __restrict__ out)          // [B]
{
    __shared__ __align__(16) float x_lds[Tsz][NBW];    // 4 KB, [t][b]
    __shared__ __align__(16) char  hA[16 * 128];       // 2 KB fp16 A-frag (rows 2..15 = 0)
    __shared__ __align__(16) float g_raw[256 * NBW];   // 2 KB, [gate][b]
    __shared__ float part[2 * NBW];

    const int tid = threadIdx.x;
    const int wv  = tid >> 6;
    const int ln  = tid & 63;
    const int col = ln & 15;
    const int grp = ln >> 4;
    const int b0  = blockIdx.x * NBW;

    constexpr float LOG2E = 1.44269504089f;
    const float s = (wv == 2) ? (-2.0f * LOG2E) : (-LOG2E);   // wave = gate type

    // ---- stage x[b0..b0+1][:] transposed into LDS: x_lds[t][b] ----
    {
        const int b  = tid >> 7;               // 128 float4 per batch row
        const int t4 = tid & 127;
        const float4 v = ((const float4*)(x + (size_t)(b0 + b) * Tsz))[t4];
        x_lds[t4 * 4 + 0][b] = v.x;
        x_lds[t4 * 4 + 1][b] = v.y;
        x_lds[t4 * 4 + 2][b] = v.z;
        x_lds[t4 * 4 + 3][b] = v.w;
    }

    // ---- W B-operand frags (one-time), pre-scaled: wave wv = gate type,
    //      tile tn covers gates wv*64 + tn*16 + col; k = kc*32 + grp*8 + e ----
    f16x8 Wf[4][2];
    float wihc[4], biasc[4];
    #pragma unroll
    for (int tn = 0; tn < 4; ++tn) {
        const int gate = wv * 64 + tn * 16 + col;
        const float* wrow = w_hh + (size_t)gate * 64;
        #pragma unroll
        for (int kc = 0; kc < 2; ++kc) {
            f16x8 w;
            #pragma unroll
            for (int e = 0; e < 8; ++e)
                w[e] = (_Float16)(wrow[kc * 32 + grp * 8 + e] * s);
            Wf[tn][kc] = w;
        }
        wihc[tn]  = w_ih[gate] * s;
        biasc[tn] = (b_ih[gate] + b_hh[gate]) * s;
    }

    // ---- A-frag (h) read offsets: row = col (batch), k = kc*32 + grp*8 + e ----
    const int sw    = (col & 7) << 4;
    const int aoff0 = col * 128 + ((grp * 16) ^ sw);
    const int aoff1 = col * 128 + ((64 + grp * 16) ^ sw);

    // ---- phase-2 ownership (tid < 128): pb = tid&1, pj = tid>>1 ----
    const int pb = tid & 1;
    const int pj = (tid >> 1) & 63;
    const float wlin  = w_lin[pj];
    const int   hwoff = pb * 128 + ((2 * pj) ^ (pb << 4));

    // zero hA (rows 2..15 must stay 0; rows 0..1 = h0 = 0): 256 x 8B = 2 KB
    ((float2*)hA)[tid] = make_float2(0.0f, 0.0f);

    float c = 0.0f, h = 0.0f;

    __syncthreads();

    for (int t = 0; t < Tsz; ++t) {
        // ===== phase 1: G = H @ W^T, C-init = x*w_ih + bias =====
        const float2 xb = *(const float2*)&x_lds[t][0];   // broadcast 8B
        const f16x8 A0 = *(const f16x8*)(hA + aoff0);
        const f16x8 A1 = *(const f16x8*)(hA + aoff1);

        f32x4 acc[4];
        #pragma unroll
        for (int tn = 0; tn < 4; ++tn) {
            acc[tn][0] = fmaf(xb.x, wihc[tn], biasc[tn]);   // row 0 = batch 0
            acc[tn][1] = fmaf(xb.y, wihc[tn], biasc[tn]);   // row 1 = batch 1
            acc[tn][2] = biasc[tn];                         // rows 2..15: discarded
            acc[tn][3] = biasc[tn];
        }
        #pragma unroll
        for (int tn = 0; tn < 4; ++tn)
            acc[tn] = __builtin_amdgcn_mfma_f32_16x16x32_f16(A0, Wf[tn][0], acc[tn], 0, 0, 0);
        #pragma unroll
        for (int tn = 0; tn < 4; ++tn)
            acc[tn] = __builtin_amdgcn_mfma_f32_16x16x32_f16(A1, Wf[tn][1], acc[tn], 0, 0, 0);

        // C layout: col = ln&15 = gate-in-tile, row = 4*grp + reg = batch.
        // Lanes 0..15 (grp 0) hold batches 0,1 in regs 0,1 -> float2 store.
        if (ln < 16) {
            #pragma unroll
            for (int tn = 0; tn < 4; ++tn) {
                float2 gw;
                gw.x = acc[tn][0];
                gw.y = acc[tn][1];
                *(float2*)&g_raw[(wv * 64 + tn * 16 + ln) * 2] = gw;
            }
        }
        __syncthreads();

        // ===== phase 2: activations, 1 state/lane on 128 threads =====
        // g_raw[(g*64+pj)*2 + pb] == g_raw[g*128 + tid] -> stride-1, conflict-free
        if (tid < 128) {
            const float gi = g_raw[tid +   0];
            const float gf = g_raw[tid + 128];
            const float gg = g_raw[tid + 256];
            const float go = g_raw[tid + 384];

            const float ig = sigm_s(gi);
            const float fg = sigm_s(gf);
            const float tg = tanh_s(gg);
            const float og = sigm_s(go);
            c = fmaf(fg, c, ig * tg);
            h = og * tanh_plain(c);

            *(_Float16*)(hA + hwoff) = (_Float16)h;
        }
        __syncthreads();
    }

    // ---- out[b0+pb] = sum_j h[pb][j]*w_lin[j] + b_lin ----
    // waves 0,1 hold states; lane = (pj&31)*2 + pb: reduce over pj bits
    if (tid < 128) {
        float p = h * wlin;
        #pragma unroll
        for (int off = 2; off < 64; off <<= 1)
            p += __shfl_xor(p, off, 64);
        if (ln < 2) part[wv * 2 + ln] = p;   // partial over this wave's 32 j's
    }
    __syncthreads();
    if (tid < NBW)
        out[b0 + tid] = part[tid] + part[2 + tid] + b_lin[0];
}

extern "C" void kernel_launch(void* const* d_in, const int* in_sizes, int n_in,
                              void* d_out, int out_size, void* d_ws, size_t ws_size,
                              hipStream_t stream) {
    const float* x     = (const float*)d_in[0];
    const float* w_ih  = (const float*)d_in[1];
    const float* w_hh  = (const float*)d_in[2];
    const float* b_ih  = (const float*)d_in[3];
    const float* b_hh  = (const float*)d_in[4];
    const float* w_lin = (const float*)d_in[5];
    const float* b_lin = (const float*)d_in[6];
    float* out = (float*)d_out;

    dim3 grid(Bsz / NBW);   // 1024
    dim3 block(256);
    lstm_v7<<<grid, block, 0, stream>>>(x, w_ih, w_hh, b_ih, b_hh,
                                        w_lin, b_lin, out);
}